// Round 3
// baseline (293.593 us; speedup 1.0000x reference)
//
#include <hip/hip_runtime.h>
#include <hip/hip_bf16.h>

#define PB 8
#define PS 1024
#define PD 512
#define PH 8

typedef __attribute__((ext_vector_type(8))) short short8;
typedef __attribute__((ext_vector_type(4))) float f32x4;

__device__ inline ushort f2bf(float x) {
    union { float f; unsigned u; } c; c.f = x;
    unsigned u = c.u + 0x7fffu + ((c.u >> 16) & 1u);
    return (ushort)(u >> 16);
}

__device__ inline void gload16(const void* g, void* l) {
    __builtin_amdgcn_global_load_lds(
        (const __attribute__((address_space(1))) void*)g,
        (__attribute__((address_space(3))) void*)l, 16, 0, 0);
}

// ---------------------------------------------------------------------------
__global__ __launch_bounds__(256)
void cast_bf16(const float* __restrict__ s, ushort* __restrict__ d, int n4)
{
    const int i = blockIdx.x * 256 + threadIdx.x;
    if (i >= n4) return;
    const float4 v = ((const float4*)s)[i];
    ushort4 o;
    o.x = f2bf(v.x); o.y = f2bf(v.y); o.z = f2bf(v.z); o.w = f2bf(v.w);
    ((ushort4*)d)[i] = o;
}

// ---------------------------------------------------------------------------
// NT GEMM: out[m,n] = sum_k A[m,k]*B[n,k] + bias[n].  A:[M][K] bf16, B:[N][K] bf16.
// MODE 0: f32 out[m*N+n].  MODE 1: bf16 head-split [(b*8+h)*1024+s][64].
// ---------------------------------------------------------------------------
template<int MODE>
__global__ __launch_bounds__(256)
void gemm_mfma(const ushort* __restrict__ A, const ushort* __restrict__ B,
               const float* __restrict__ bias, void* __restrict__ out,
               int M, int N, int K)
{
    __shared__ __align__(16) ushort As[128 * 64];
    __shared__ __align__(16) ushort Bs[128 * 64];
    const int tid = threadIdx.x;
    const int lane = tid & 63;
    const int wave = tid >> 6;
    const int wr = wave >> 1, wc = wave & 1;
    const int bm = blockIdx.x * 128, bn = blockIdx.y * 128;
    const int lrow = lane >> 3;
    const int lcol = (lane & 7) * 8;

    f32x4 acc[4][4] = {};

    for (int k0 = 0; k0 < K; k0 += 64) {
#pragma unroll
        for (int i = 0; i < 4; ++i) {
            const int c = wave * 4 + i;
            gload16(A + (size_t)(bm + c * 8 + lrow) * K + k0 + lcol, &As[c * 512]);
            gload16(B + (size_t)(bn + c * 8 + lrow) * K + k0 + lcol, &Bs[c * 512]);
        }
        __syncthreads();
        short8 af[2][4], bf[2][4];
#pragma unroll
        for (int kk = 0; kk < 2; ++kk) {
#pragma unroll
            for (int m = 0; m < 4; ++m)
                af[kk][m] = *(const short8*)&As[(wr * 64 + m * 16 + (lane & 15)) * 64 + kk * 32 + (lane >> 4) * 8];
#pragma unroll
            for (int n = 0; n < 4; ++n)
                bf[kk][n] = *(const short8*)&Bs[(wc * 64 + n * 16 + (lane & 15)) * 64 + kk * 32 + (lane >> 4) * 8];
        }
#pragma unroll
        for (int kk = 0; kk < 2; ++kk)
#pragma unroll
            for (int m = 0; m < 4; ++m)
#pragma unroll
                for (int n = 0; n < 4; ++n)
                    acc[m][n] = __builtin_amdgcn_mfma_f32_16x16x32_bf16(af[kk][m], bf[kk][n], acc[m][n], 0, 0, 0);
        __syncthreads();
    }

#pragma unroll
    for (int m = 0; m < 4; ++m)
#pragma unroll
        for (int n = 0; n < 4; ++n)
#pragma unroll
            for (int r = 0; r < 4; ++r) {
                const int row = bm + wr * 64 + m * 16 + (lane >> 4) * 4 + r;
                const int col = bn + wc * 64 + n * 16 + (lane & 15);
                const float v = acc[m][n][r] + bias[col];
                if (MODE == 0) {
                    ((float*)out)[(size_t)row * N + col] = v;
                } else {
                    const int b = row >> 10, s = row & 1023;
                    const int h = col >> 6, d = col & 63;
                    ((ushort*)out)[(((size_t)(b * 8 + h)) * 1024 + s) * 64 + d] = f2bf(v);
                }
            }
}

// ---------------------------------------------------------------------------
// Fused attention: block = (b,h, 16-query-row block), 16 waves, row per wave.
// QK^T (MFMA, tile pairs) -> register logits -> softmax1/cumsum/decay/softmax2
// -> nontemporal scores write -> PV (MFMA, K-split) -> bf16 concat output.
// ---------------------------------------------------------------------------
__global__ __launch_bounds__(1024)
void attn_fused(const ushort* __restrict__ qh, const ushort* __restrict__ kh,
                const ushort* __restrict__ vh, const float* __restrict__ gammas,
                float* __restrict__ scores, ushort* __restrict__ attn)
{
    const int qb = blockIdx.x, bh = blockIdx.y;
    const int b = bh >> 3, h = bh & 7;
    const int tid = threadIdx.x, lane = tid & 63, wave = tid >> 6;
    const int T = (qb >> 2) + 1;            // k-tiles of 64 up to the diagonal
    const int i = qb * 16 + wave;           // this wave's query row
    const int n = wave & 3, kk = (wave >> 2) & 1, par = wave >> 3;

    __shared__ __align__(16) ushort Q[16 * 64];       // 2 KB
    __shared__ __align__(16) ushort KV[2][64 * 64];   // 16 KB (K tiles, then V)
    __shared__ __align__(16) ushort P2[2][16 * 64];   // 4 KB (swizzled)
    __shared__ float SP[2][2][16][64];                // 16 KB
    __shared__ float RED[4][16][64];                  // 16 KB

    const ushort* qbase = qh + (((size_t)bh << 10) + (size_t)qb * 16) * 64;
    const ushort* kbase = kh + ((size_t)bh << 16);
    const ushort* vbase = vh + ((size_t)bh << 16);

    if (tid < 128) gload16(qbase + tid * 8, &Q[tid * 8]);

    float l[16], cum[16];
#pragma unroll
    for (int c = 0; c < 16; ++c) { l[c] = -3.0e38f; cum[c] = 0.f; }

    const int sidx = tid & 511, sbuf = tid >> 9;

    // ---------------- QK phase (2 k-tiles per iteration) ----------------
    for (int ktp = 0; ktp < T; ktp += 2) {
        const int ts = ktp + sbuf;
        if (ts < T) gload16(kbase + ((size_t)ts << 12) + sidx * 8, &KV[sbuf][sidx * 8]);
        __syncthreads();                     // K staged (vmcnt drained), prev SP reads done
        const int t = ktp + par;
        if (t < T) {
            const short8 af = *(const short8*)&Q[(lane & 15) * 64 + kk * 32 + (lane >> 4) * 8];
            const short8 bf = *(const short8*)&KV[par][(n * 16 + (lane & 15)) * 64 + kk * 32 + (lane >> 4) * 8];
            f32x4 z = {};
            z = __builtin_amdgcn_mfma_f32_16x16x32_bf16(af, bf, z, 0, 0, 0);
#pragma unroll
            for (int r = 0; r < 4; ++r)
                SP[par][kk][(lane >> 4) * 4 + r][n * 16 + (lane & 15)] = z[r];
        }
        __syncthreads();                     // SP ready, KV reads done
#pragma unroll
        for (int u = 0; u < 2; ++u) {
            const int c = ktp + u;
            if (c < T) {
                const float s = (SP[u][0][wave][lane] + SP[u][1][wave][lane]) * 0.125f;
                l[c] = (c * 64 + lane <= i) ? s : -3.0e38f;
            }
        }
    }

    // ---------------- softmax1 ----------------
    const float gamma = -fabsf(gammas[h]);
    float m1 = -3.0e38f;
#pragma unroll
    for (int c = 0; c < 16; ++c) m1 = fmaxf(m1, l[c]);
#pragma unroll
    for (int off = 32; off; off >>= 1) m1 = fmaxf(m1, __shfl_xor(m1, off));

    float es = 0.f;
#pragma unroll
    for (int c = 0; c < 16; ++c) { if (c >= T) break; es += __expf(l[c] - m1); }
#pragma unroll
    for (int off = 32; off; off >>= 1) es += __shfl_xor(es, off);
    const float inv1 = 1.0f / es;

    // ---------------- cumsum over normalized probs ----------------
    float run = 0.f;
#pragma unroll
    for (int c = 0; c < 16; ++c) {
        if (c >= T) break;
        float x = __expf(l[c] - m1) * inv1;
#pragma unroll
        for (int off = 1; off < 64; off <<= 1) {
            const float y = __shfl_up(x, off);
            if (lane >= off) x += y;
        }
        cum[c] = run + x;
        run += __shfl(x, 63);
    }
    const float dt = run;

    // ---------------- decay + softmax2 ----------------
#pragma unroll
    for (int c = 0; c < 16; ++c) {
        if (c >= T) break;
        const float pe = (float)(i - (c * 64 + lane));       // <0 for masked lanes
        const float sfx = fmaxf(dt - cum[c], 0.f);
        const float dist = sqrtf(fmaxf(sfx * pe, 0.f));
        const float eff = fmaxf(__expf(gamma * dist), 1e-5f);
        l[c] = l[c] * eff;                                    // masked stays -3e38
    }

    float m2 = -3.0e38f;
#pragma unroll
    for (int c = 0; c < 16; ++c) m2 = fmaxf(m2, l[c]);
#pragma unroll
    for (int off = 32; off; off >>= 1) m2 = fmaxf(m2, __shfl_xor(m2, off));

    float s2 = 0.f;
#pragma unroll
    for (int c = 0; c < 16; ++c) { l[c] = __expf(l[c] - m2); s2 += l[c]; }
#pragma unroll
    for (int off = 32; off; off >>= 1) s2 += __shfl_xor(s2, off);
    const float inv2 = 1.0f / s2;
#pragma unroll
    for (int c = 0; c < 16; ++c) l[c] *= inv2;                // c>=T -> exact 0

    // ---------------- scores write (nontemporal, write-once) ----------------
    {
        float* srow = scores + ((size_t)bh << 20) + ((size_t)i << 10);
#pragma unroll
        for (int c = 0; c < 16; ++c)
            __builtin_nontemporal_store(l[c], &srow[c * 64 + lane]);
    }

    // ---------------- PV phase ----------------
    f32x4 acc = {};
    const int psl = (((lane >> 3) ^ (wave & 7)) << 3) + (lane & 7);  // swizzled slot
    for (int ktp = 0; ktp < T; ktp += 2) {
        const int ts = ktp + sbuf;
        if (ts < T) gload16(vbase + ((size_t)ts << 12) + sidx * 8, &KV[sbuf][sidx * 8]);
#pragma unroll
        for (int u = 0; u < 2; ++u) {
            const int c = ktp + u;
            if (c < T) P2[u][wave * 64 + psl] = f2bf(l[c]);
        }
        __syncthreads();                     // V + P staged, prev reads done
        const int t = ktp + par;
        if (t < T) {
            const int row = lane & 15;
            const int slot = (((kk * 4 + (lane >> 4)) ^ (row & 7)) << 3);
            const short8 af = *(const short8*)&P2[par][row * 64 + slot];
            short8 bv;
#pragma unroll
            for (int j = 0; j < 8; ++j)
                bv[j] = (short)KV[par][(kk * 32 + (lane >> 4) * 8 + j) * 64 + n * 16 + row];
            acc = __builtin_amdgcn_mfma_f32_16x16x32_bf16(af, bv, acc, 0, 0, 0);
        }
        __syncthreads();                     // KV/P2 reads done before restage
    }

    // ---------------- reduce partials + write concat output ----------------
#pragma unroll
    for (int r = 0; r < 4; ++r)
        RED[par * 2 + kk][(lane >> 4) * 4 + r][n * 16 + (lane & 15)] = acc[r];
    __syncthreads();
    if (wave < 4) {
#pragma unroll
        for (int r = 0; r < 4; ++r) {
            const int row = (lane >> 4) * 4 + r;
            const int col = wave * 16 + (lane & 15);
            const float o = RED[0][row][col] + RED[1][row][col] +
                            RED[2][row][col] + RED[3][row][col];
            attn[((size_t)(b * 1024 + qb * 16 + row)) * 512 + h * 64 + col] = f2bf(o);
        }
    }
}

// ---------------------------------------------------------------------------
extern "C" void kernel_launch(void* const* d_in, const int* in_sizes, int n_in,
                              void* d_out, int out_size, void* d_ws, size_t ws_size,
                              hipStream_t stream)
{
    const float* q      = (const float*)d_in[0];
    const float* k      = (const float*)d_in[1];
    const float* v      = (const float*)d_in[2];
    const float* Wq     = (const float*)d_in[4];
    const float* bq     = (const float*)d_in[5];
    const float* Wv     = (const float*)d_in[6];
    const float* bv     = (const float*)d_in[7];
    const float* Wo     = (const float*)d_in[8];
    const float* bo     = (const float*)d_in[9];
    const float* gammas = (const float*)d_in[10];

    float* out    = (float*)d_out;                       // [8,1024,512] f32
    float* scores = out + (size_t)PB * PS * PD;          // [64,1024,1024] f32

    char* w = (char*)d_ws;
    ushort* q_bf  = (ushort*)(w);
    ushort* k_bf  = (ushort*)(w + (8u  << 20));
    ushort* v_bf  = (ushort*)(w + (16u << 20));
    ushort* Wq_bf = (ushort*)(w + (24u << 20));
    ushort* Wv_bf = (ushort*)(w + (25u << 20));
    ushort* Wo_bf = (ushort*)(w + (26u << 20));
    ushort* qh    = (ushort*)(w + (27u << 20));
    ushort* kh    = (ushort*)(w + (35u << 20));
    ushort* vh    = (ushort*)(w + (43u << 20));
    ushort* attn  = (ushort*)(w + (51u << 20));

    cast_bf16<<<4096, 256, 0, stream>>>(q, q_bf, 1048576);
    cast_bf16<<<4096, 256, 0, stream>>>(k, k_bf, 1048576);
    cast_bf16<<<4096, 256, 0, stream>>>(v, v_bf, 1048576);
    cast_bf16<<<256, 256, 0, stream>>>(Wq, Wq_bf, 65536);
    cast_bf16<<<256, 256, 0, stream>>>(Wv, Wv_bf, 65536);
    cast_bf16<<<256, 256, 0, stream>>>(Wo, Wo_bf, 65536);

    gemm_mfma<1><<<dim3(64, 4), 256, 0, stream>>>(q_bf, Wq_bf, bq, qh, 8192, 512, 512);
    gemm_mfma<1><<<dim3(64, 4), 256, 0, stream>>>(k_bf, Wq_bf, bq, kh, 8192, 512, 512);
    gemm_mfma<1><<<dim3(64, 4), 256, 0, stream>>>(v_bf, Wv_bf, bv, vh, 8192, 512, 512);

    attn_fused<<<dim3(64, 64), 1024, 0, stream>>>(qh, kh, vh, gammas, scores, attn);

    gemm_mfma<0><<<dim3(64, 4), 256, 0, stream>>>(attn, Wo_bf, bo, out, 8192, 512, 512);
}